// Round 11
// baseline (706.579 us; speedup 1.0000x reference)
//
#include <hip/hip_runtime.h>
#include <hip/hip_bf16.h>

// Autoregressive LSTM: B=16384, T=60, D=34, E=128, H=64, n_seeds=10
// R11: wave-autonomous (R9 dataflow, numerics validated) with LDS addressing
// engineered for 16-bit ds offsets: weights stored lr-major so every read is
// one shared vaddr + compile-time immediate (<64KB absolute). This kills R9's
// ~100 materialized address VGPRs (the actual spill cause; FETCH was 1.15GB).
// 256 blocks x 256 thr (1/CU), wave owns 16 batch rows, no in-loop barriers.

typedef float f32x4 __attribute__((ext_vector_type(4)));
typedef __bf16 bf16x8 __attribute__((ext_vector_type(8)));
typedef unsigned short u16x8 __attribute__((ext_vector_type(8)));
typedef unsigned short u16x4 __attribute__((ext_vector_type(4)));

#define MFMA_BF16(A, B, C) \
    __builtin_amdgcn_mfma_f32_16x16x32_bf16(__builtin_bit_cast(bf16x8, (A)), \
                                            __builtin_bit_cast(bf16x8, (B)), (C), 0, 0, 0)

__device__ __forceinline__ unsigned short f2b(float f) {
    return __builtin_bit_cast(unsigned short, (__bf16)f);
}
__device__ __forceinline__ unsigned pack2(float a, float b) {
    return (unsigned)f2b(a) | ((unsigned)f2b(b) << 16);
}
__device__ __forceinline__ float exp2_(float x) {
#if __has_builtin(__builtin_amdgcn_exp2f)
    return __builtin_amdgcn_exp2f(x);
#else
    return __exp2f(x);
#endif
}
__device__ __forceinline__ float rcp_(float x) { return __builtin_amdgcn_rcpf(x); }
__device__ __forceinline__ float sig_(float x) {
    return rcp_(1.0f + exp2_(-1.44269504f * x));
}
__device__ __forceinline__ float tanh_(float x) {
    return __builtin_fmaf(2.0f, rcp_(1.0f + exp2_(-2.88539008f * x)), -1.0f);
}

// u16 strides (lr-major weight layouts; +8 u16 pad => dword-stride ≡ 4 mod 32)
#define WG_LRS 3208   // 16 rows x 200 + 8 pad  (6416 B, 16B-aligned)
#define WP_LRS 584    // 8 rows x 72 + 8 pad    (1168 B, 16B-aligned)

__global__ __launch_bounds__(256, 1) void ar_lstm_kernel(
    const float* __restrict__ x,      // (16384,60,34)
    const float* __restrict__ W_enc,  // (128,34)
    const float* __restrict__ b_enc,  // (128)
    const float* __restrict__ W_ih,   // (256,128)
    const float* __restrict__ W_hh,   // (256,64)
    const float* __restrict__ b_ih,   // (256)
    const float* __restrict__ b_hh,   // (256)
    const float* __restrict__ W_dec,  // (34,64)
    const float* __restrict__ b_dec,  // (34)
    float* __restrict__ out)          // (16384,50,34)
{
    // Declaration order matters: per-wave buffers + tables first (small
    // offsets), Wp next, the 102KB Wg last -> all ds immediates < 64KB.
    __shared__ __attribute__((aligned(16))) unsigned short xtr[4][16][136]; // per-wave rnn_in
    __shared__ __attribute__((aligned(16))) unsigned short htr[4][16][72];  // per-wave h
    __shared__ float bias_g_tab[256];
    __shared__ float bias_f_tab[128];
    __shared__ __attribute__((aligned(16))) unsigned short Wp_s[16 * WP_LRS];
    __shared__ __attribute__((aligned(16))) unsigned short Wg_s[16 * WG_LRS];

    const int tid = threadIdx.x;
    const int wv = tid >> 6;
    const int l  = tid & 63;
    const int lr = l & 15;
    const int lg = l >> 4;
    const int rowbase = blockIdx.x * 64 + wv * 16;

    // ===================== init (2 barriers total) =====================
    float* wdec_s = (float*)&xtr[0][0][0];   // 8704B f32 scratch inside xtr
    for (int i = tid; i < 34 * 64; i += 256) wdec_s[i] = W_dec[i];
    {   // weight row n -> Wg_s[(n&15)*WG_LRS + (n>>4)*200 + k]
        const int n = tid;
        unsigned short* dst = &Wg_s[(n & 15) * WG_LRS + (n >> 4) * 200];
        const float* wi = &W_ih[n * 128];
        for (int k = 0; k < 128; k += 2) *(unsigned*)&dst[k] = pack2(wi[k], wi[k + 1]);
        const float* wh = &W_hh[n * 64];
        for (int k = 0; k < 64; k += 2) *(unsigned*)&dst[128 + k] = pack2(wh[k], wh[k + 1]);
        for (int k = 192; k < 200; k += 2) *(unsigned*)&dst[k] = 0;
        bias_g_tab[n] = b_ih[n] + b_hh[n];
    }
    __syncthreads();
    if (tid < 128) {   // Wp row n = W_enc[n,:] @ W_dec -> Wp_s[(n&15)*WP_LRS + (n>>4)*72 + k]
        const int n = tid;
        const float* we_row = &W_enc[n * 34];
        float bs = b_enc[n];
        for (int j = 0; j < 34; ++j) bs += we_row[j] * b_dec[j];
        bias_f_tab[n] = bs;
        unsigned short* dst = &Wp_s[(n & 15) * WP_LRS + (n >> 4) * 72];
        for (int k = 0; k < 64; k += 2) {
            float s0 = 0.0f, s1 = 0.0f;
            for (int j = 0; j < 34; ++j) {
                float w = we_row[j];
                s0 += w * wdec_s[j * 64 + k];
                s1 += w * wdec_s[j * 64 + k + 1];
            }
            *(unsigned*)&dst[k] = pack2(s0, s1);
        }
        for (int k = 64; k < 72; k += 2) *(unsigned*)&dst[k] = 0;
    }
    __syncthreads();   // tables done; xtr scratch free. No barriers after this.

    // ---- persistent registers ----
    u16x8 wd[3][2];
    float bias_d[3];
    #pragma unroll
    for (int nt = 0; nt < 3; ++nt) {
        int n = nt * 16 + lr;
        bool v = n < 34;
        bias_d[nt] = v ? b_dec[n] : 0.0f;
        #pragma unroll
        for (int kt = 0; kt < 2; ++kt)
            #pragma unroll
            for (int i = 0; i < 8; ++i)
                wd[nt][kt][i] = v ? f2b(W_dec[n * 64 + kt * 32 + lg * 8 + i]) : (unsigned short)0;
    }
    u16x8 ax[4], ahh[2];
    #pragma unroll
    for (int kt = 0; kt < 4; ++kt)
        #pragma unroll
        for (int i = 0; i < 8; ++i) ax[kt][i] = 0;
    #pragma unroll
    for (int kt = 0; kt < 2; ++kt)
        #pragma unroll
        for (int i = 0; i < 8; ++i) ahh[kt][i] = 0;
    float c_st[4][4];
    #pragma unroll
    for (int a = 0; a < 4; ++a)
        #pragma unroll
        for (int r = 0; r < 4; ++r) c_st[a][r] = 0.0f;

    // single dynamic vaddrs (all reads below = vaddr + compile-time immediate)
    const unsigned short* wgrow = &Wg_s[lr * WG_LRS + lg * 8];
    const unsigned short* wprow = &Wp_s[lr * WP_LRS + lg * 8];

    // gates + cell: reads ax/ahh regs + Wg_s, updates c_st, refreshes ahh
    auto GATES = [&]() {
        #pragma unroll
        for (int jt = 0; jt < 4; ++jt) {
            f32x4 acc0 = *(const f32x4*)&bias_g_tab[(0 * 4 + jt) * 16 + lg * 4];
            f32x4 acc1 = *(const f32x4*)&bias_g_tab[(1 * 4 + jt) * 16 + lg * 4];
            f32x4 acc2 = *(const f32x4*)&bias_g_tab[(2 * 4 + jt) * 16 + lg * 4];
            f32x4 acc3 = *(const f32x4*)&bias_g_tab[(3 * 4 + jt) * 16 + lg * 4];
            #pragma unroll
            for (int kt = 0; kt < 6; ++kt) {
                u16x8 bfr = (kt < 4) ? ax[kt] : ahh[kt - 4];
                acc0 = MFMA_BF16(*(const u16x8*)&wgrow[(0 * 4 + jt) * 200 + kt * 32], bfr, acc0);
                acc1 = MFMA_BF16(*(const u16x8*)&wgrow[(1 * 4 + jt) * 200 + kt * 32], bfr, acc1);
                acc2 = MFMA_BF16(*(const u16x8*)&wgrow[(2 * 4 + jt) * 200 + kt * 32], bfr, acc2);
                acc3 = MFMA_BF16(*(const u16x8*)&wgrow[(3 * 4 + jt) * 200 + kt * 32], bfr, acc3);
            }
            u16x4 hv;
            #pragma unroll
            for (int r = 0; r < 4; ++r) {
                float cn = sig_(acc1[r]) * c_st[jt][r] + sig_(acc0[r]) * tanh_(acc2[r]);
                float hn = sig_(acc3[r]) * tanh_(cn);
                c_st[jt][r] = cn;
                hv[r] = f2b(hn);
            }
            *(u16x4*)&htr[wv][lr][jt * 16 + lg * 4] = hv;
        }
        ahh[0] = *(const u16x8*)&htr[wv][lr][lg * 8];
        ahh[1] = *(const u16x8*)&htr[wv][lr][32 + lg * 8];
    };
    // enc': rnn_in = relu(W' h + b') -> xtr -> ax
    auto ENCP = [&]() {
        #pragma unroll
        for (int ntl = 0; ntl < 8; ++ntl) {
            f32x4 a = *(const f32x4*)&bias_f_tab[ntl * 16 + lg * 4];
            a = MFMA_BF16(*(const u16x8*)&wprow[ntl * 72],      ahh[0], a);
            a = MFMA_BF16(*(const u16x8*)&wprow[ntl * 72 + 32], ahh[1], a);
            u16x4 pv;
            #pragma unroll
            for (int r = 0; r < 4; ++r) pv[r] = f2b(fmaxf(a[r], 0.0f));
            *(u16x4*)&xtr[wv][lr][ntl * 16 + lg * 4] = pv;
        }
        #pragma unroll
        for (int kt = 0; kt < 4; ++kt)
            ax[kt] = *(const u16x8*)&xtr[wv][lr][kt * 32 + lg * 8];
    };

    // ===================== seed loop (t = 0..9) =====================
    {
        u16x8 wet[8][2];   // scoped: freed before the AR loop
        #pragma unroll
        for (int ntl = 0; ntl < 8; ++ntl) {
            int n = ntl * 16 + lr;
            #pragma unroll
            for (int kt = 0; kt < 2; ++kt)
                #pragma unroll
                for (int i = 0; i < 8; ++i) {
                    int k = kt * 32 + lg * 8 + i;
                    wet[ntl][kt][i] = (k < 34) ? f2b(W_enc[n * 34 + k]) : (unsigned short)0;
                }
        }
        for (int t = 0; t < 10; ++t) {
            const float* xf = &x[(size_t)(rowbase + lr) * 2040 + t * 34];
            u16x8 bd0, bd1;
            #pragma unroll
            for (int i = 0; i < 8; ++i) bd0[i] = f2b(xf[lg * 8 + i]);
            #pragma unroll
            for (int i = 0; i < 8; ++i) bd1[i] = 0;
            if (lg == 0) { bd1[0] = f2b(xf[32]); bd1[1] = f2b(xf[33]); }
            #pragma unroll
            for (int ntl = 0; ntl < 8; ++ntl) {
                f32x4 a = *(const f32x4*)&b_enc[ntl * 16 + lg * 4];
                a = MFMA_BF16(wet[ntl][0], bd0, a);
                a = MFMA_BF16(wet[ntl][1], bd1, a);
                u16x4 pv;
                #pragma unroll
                for (int r = 0; r < 4; ++r) pv[r] = f2b(fmaxf(a[r], 0.0f));
                *(u16x4*)&xtr[wv][lr][ntl * 16 + lg * 4] = pv;
            }
            #pragma unroll
            for (int kt = 0; kt < 4; ++kt)
                ax[kt] = *(const u16x8*)&xtr[wv][lr][kt * 32 + lg * 8];
            GATES();
        }
    }

    // ---- transition: prev = x[:,9,:]; rnn_in for t=10 ----
    float prev[3][4];
    #pragma unroll
    for (int nt = 0; nt < 3; ++nt) {
        int cidx = nt * 16 + lr;
        #pragma unroll
        for (int r = 0; r < 4; ++r)
            prev[nt][r] = (cidx < 34)
                ? x[(size_t)(rowbase + lg * 4 + r) * 2040 + 9 * 34 + cidx] : 0.0f;
    }
    ENCP();
    float* orow[4];
    #pragma unroll
    for (int r = 0; r < 4; ++r)
        orow[r] = out + (size_t)(rowbase + lg * 4 + r) * 1700;

    // ===================== AR loop (t = 10..59) =====================
    int toff = 0;
    for (int t = 10; t < 60; ++t) {
        GATES();
        #pragma unroll
        for (int nt = 0; nt < 3; ++nt) {
            f32x4 a = { bias_d[nt], bias_d[nt], bias_d[nt], bias_d[nt] };
            a = MFMA_BF16(ahh[0], wd[nt][0], a);
            a = MFMA_BF16(ahh[1], wd[nt][1], a);
            int cidx = nt * 16 + lr;
            if (cidx < 34)
                #pragma unroll
                for (int r = 0; r < 4; ++r) {
                    float o = a[r] + prev[nt][r];
                    prev[nt][r] = o;
                    orow[r][toff + cidx] = o;
                }
        }
        toff += 34;
        if (t < 59) ENCP();
    }
}

extern "C" void kernel_launch(void* const* d_in, const int* in_sizes, int n_in,
                              void* d_out, int out_size, void* d_ws, size_t ws_size,
                              hipStream_t stream) {
    const float* x     = (const float*)d_in[0];
    const float* W_enc = (const float*)d_in[1];
    const float* b_enc = (const float*)d_in[2];
    const float* W_ih  = (const float*)d_in[3];
    const float* W_hh  = (const float*)d_in[4];
    const float* b_ih  = (const float*)d_in[5];
    const float* b_hh  = (const float*)d_in[6];
    const float* W_dec = (const float*)d_in[7];
    const float* b_dec = (const float*)d_in[8];
    float* out = (float*)d_out;
    // n_seeds (d_in[9]) is compile-time 10 for this problem shape.
    ar_lstm_kernel<<<256, 256, 0, stream>>>(x, W_enc, b_enc, W_ih, W_hh,
                                            b_ih, b_hh, W_dec, b_dec, out);
}